// Round 6
// baseline (800.975 us; speedup 1.0000x reference)
//
#include <hip/hip_runtime.h>
#include <math.h>

#define Bsz 32
#define Nn 207
#define Tt 12
#define Cc 2
#define HORr 12
#define DIDd 64
#define Hh 128
#define NBb 3
#define CONCATk 2560
#define BN (Bsz*Nn)           // 6624
#define ROWS (BN*Cc)          // 13248 = 828*16 = 207*64
#define XSTRIDE (CONCATk*Cc)  // 5120

typedef unsigned short u16;
typedef __attribute__((ext_vector_type(8))) short bf16x8;
typedef __attribute__((ext_vector_type(4))) float f32x4;

__device__ inline u16 f2b(float f) {
  unsigned u = __builtin_bit_cast(unsigned, f);
  u += 0x7fffu + ((u >> 16) & 1u);          // RNE
  return (u16)(u >> 16);
}
__device__ inline float b2f(u16 b) {
  unsigned u = ((unsigned)b) << 16;
  return __builtin_bit_cast(float, u);
}

// ---------------- K1: time gates + h_in + level + zero f_acc ----------------
__global__ __launch_bounds__(128) void k_timegate(
    const float* __restrict__ hist, const float* __restrict__ tod,
    const float* __restrict__ emb,
    const float* __restrict__ w1, const float* __restrict__ b1,
    const float* __restrict__ w2, const float* __restrict__ b2,
    const float* __restrict__ w3, const float* __restrict__ b3,
    float* __restrict__ h_in, float* __restrict__ level,
    float* __restrict__ tgf, float* __restrict__ f_acc)
{
  int bn = blockIdx.x;
  int n = bn % Nn;
  __shared__ float s_in[76];
  __shared__ float s_tg[128];
  __shared__ float s_tgb[12];
  __shared__ float s_h[24];
  __shared__ float part[24][4];
  int tid = threadIdx.x;
  if (tid < 64) s_in[tid] = emb[n*64 + tid];
  else if (tid < 76) s_in[tid] = tod[bn*12 + (tid - 64)];
  __syncthreads();
  float acc = b1[tid];
#pragma unroll 4
  for (int k = 0; k < 76; ++k) acc = fmaf(s_in[k], w1[k*128 + tid], acc);
  s_tg[tid] = fmaxf(acc, 0.f);
  __syncthreads();
  if (tid < 96) {
    int j = tid >> 2, p = tid & 3;
    int jj = (j < 12) ? j : j - 12;
    const float* w = (j < 12) ? w2 : w3;
    float a = 0.f;
#pragma unroll 8
    for (int k = p*32; k < p*32 + 32; ++k) a = fmaf(s_tg[k], w[k*12 + jj], a);
    part[j][p] = a;
  }
  __syncthreads();
  if (tid < 24) {
    int jj = (tid < 12) ? tid : tid - 12;
    float a = ((tid < 12) ? b2[jj] : b3[jj])
            + part[tid][0] + part[tid][1] + part[tid][2] + part[tid][3];
    if (tid < 12) tgf[bn*12 + jj] = a;
    else s_tgb[jj] = a;
  }
  __syncthreads();
  if (tid < 24) {
    int t = tid >> 1;
    float v = hist[bn*24 + tid] / (1.f + s_tgb[t]);
    h_in[bn*24 + tid] = v;
    s_h[tid] = v;
    f_acc[bn*24 + tid] = 0.f;
  }
  __syncthreads();
  if (tid < 2) {
    float m = s_h[tid];
    for (int t = 1; t < 12; ++t) m = fmaxf(m, s_h[t*2 + tid]);
    level[bn*2 + tid] = m;
  }
}

// ---------------- K2: dp[n,m] = exp(10 * <emb_n, emb_m>) ----------------
__global__ __launch_bounds__(256) void k_dp(const float* __restrict__ emb,
                                            float* __restrict__ dp)
{
  int n = blockIdx.x;
  __shared__ float e[64];
  int tid = threadIdx.x;
  if (tid < 64) e[tid] = emb[n*64 + tid];
  __syncthreads();
  if (tid < Nn) {
    float a = 0.f;
#pragma unroll 8
    for (int k = 0; k < 64; ++k) a = fmaf(e[k], emb[tid*64 + k], a);
    dp[n*Nn + tid] = expf(10.f * a);
  }
}

// ---------------- weight transpose+convert: fp32 [K][N] -> bf16 [N][K] -------
__global__ __launch_bounds__(256) void k_transp(
    const float* __restrict__ src, u16* __restrict__ dst, int K, int N)
{
  int k0 = blockIdx.x*64, n0 = blockIdx.y*64;
  size_t mo = (size_t)blockIdx.z * K * N;
  src += mo; dst += mo;
  __shared__ u16 Ts[64][72];
  int tid = threadIdx.x;
#pragma unroll
  for (int it = 0; it < 4; ++it) {
    int idx = it*256 + tid;
    int r = idx >> 4, q = idx & 15;
    float4 v = *(const float4*)(src + (size_t)(k0 + r)*N + n0 + q*4);
    Ts[r][q*4+0] = f2b(v.x);
    Ts[r][q*4+1] = f2b(v.y);
    Ts[r][q*4+2] = f2b(v.z);
    Ts[r][q*4+3] = f2b(v.w);
  }
  __syncthreads();
#pragma unroll
  for (int it = 0; it < 2; ++it) {
    int idx = it*256 + tid;
    int nl = idx >> 3, kq = idx & 7;
    u16 o[8];
#pragma unroll
    for (int j = 0; j < 8; ++j) o[j] = Ts[kq*8 + j][nl];
    *(bf16x8*)(dst + (size_t)(n0 + nl)*K + k0 + kq*8) = *(bf16x8*)o;
  }
}

// ---------------- build xb bf16, row-major [r=bn*2+c][k] ---------------------
__global__ __launch_bounds__(256) void k_build_b(
    const float* __restrict__ h_in, const float* __restrict__ level,
    const float* __restrict__ dp, const float* __restrict__ emb,
    u16* __restrict__ xb)
{
  int bn = blockIdx.x;
  int b = bn / Nn, n = bn - b*Nn;
  __shared__ float s_dp[Nn];
  __shared__ __attribute__((aligned(16))) u16 row[2][2560];
  int tid = threadIdx.x;
  for (int m = tid; m < Nn; m += 256) s_dp[m] = dp[n*Nn + m];
  float lev0 = level[bn*2], lev1 = level[bn*2+1];
  float inv0 = 1.f/(lev0+1e-8f), inv1 = 1.f/(lev1+1e-8f);
  __syncthreads();
  if (tid < Nn) {
    int m = tid;
    float dpm = s_dp[m];
    const float2* hp = (const float2*)(h_in + (size_t)(b*Nn + m)*24);
#pragma unroll
    for (int t = 0; t < 12; ++t) {
      float2 v = hp[t];
      row[0][12 + m*12 + t] = f2b(fmaxf((v.x*dpm - lev0)*inv0, 0.f));
      row[1][12 + m*12 + t] = f2b(fmaxf((v.y*dpm - lev1)*inv1, 0.f));
    }
  } else if (tid < 219) {            // history (12 t, both c)
    int t = tid - 207;
    float2 v = *(const float2*)(h_in + (size_t)bn*24 + t*2);
    row[0][t] = f2b(v.x*inv0);
    row[1][t] = f2b(v.y*inv1);
  } else if (tid < 251) {            // emb: 32 threads x 2 elems
    int e = (tid - 219)*2;
    float2 ev = *(const float2*)(emb + n*64 + e);
    u16 a = f2b(ev.x), bq = f2b(ev.y);
    row[0][2496+e] = a; row[0][2497+e] = bq;
    row[1][2496+e] = a; row[1][2497+e] = bq;
  }
  __syncthreads();
  for (int s = tid; s < 640; s += 256) {
    int c = s >= 320, ks = s - c*320;
    *(bf16x8*)(xb + (size_t)(bn*2 + c)*2560 + ks*8) = *(const bf16x8*)&row[c][ks*8];
  }
}

// ---------------- k_fc: fc0 -> h1 -> h2 -> h3 + fore; writes h3 --------------
// Round-6: zero-LDS fc0. B-panels have no intra-block reuse, so LDS staging of
// them was pure prefetch bought with barriers + the gld16 drain chain (the
// ~25 GB/s/CU "law" was that chain's emergent rate). Now: 16-row tiles, grid
// 828 (~3.2 blk/CU, 13 waves/CU), fc0 loop loads A/B fragments straight
// global->VGPR into an explicit ping-pong register double-buffer (addressing
// identical to R3's HW-validated direct kernel; R3's failure was its absent
// pipeline, VGPR=40). No barriers in fc0; LDS = 4KB h-tile only.
__global__ __launch_bounds__(256, 4) void k_fc(
    const u16* __restrict__ xb,
    const u16* __restrict__ W0t, const float* __restrict__ b0,
    const u16* __restrict__ W1t, const float* __restrict__ b1,
    const u16* __restrict__ W2t, const float* __restrict__ b2,
    const float* __restrict__ FW, const float* __restrict__ fb,
    float* __restrict__ f_acc, u16* __restrict__ h3)
{
  __shared__ __attribute__((aligned(16))) u16 Hs[16*16*8];  // 4 KB h tile
  __shared__ __attribute__((aligned(16))) u16 sFw[1536];    // 3 KB FW bf16
  __shared__ float sFb[12];
  const int tid = threadIdx.x, wv = tid >> 6, lane = tid & 63;
  const int m16 = lane & 15, quad = lane >> 4;
  const int wc = wv * 32;                 // per-wave col group of 128
  const int r0 = blockIdx.x * 16;

  const u16* arow = xb  + (size_t)(r0 + m16)*2560 + quad*8;
  const u16* cb0  = W0t + (size_t)(wc      + m16)*2560 + quad*8;
  const u16* cb1  = W0t + (size_t)(wc + 16 + m16)*2560 + quad*8;

  f32x4 acc0 = {}, acc1 = {};
  auto ldf = [&](bf16x8 (&a)[2], bf16x8 (&b)[4], int T) {
    a[0] = *(const bf16x8*)(arow + T*64);
    a[1] = *(const bf16x8*)(arow + T*64 + 32);
    b[0] = *(const bf16x8*)(cb0 + T*64);
    b[1] = *(const bf16x8*)(cb1 + T*64);
    b[2] = *(const bf16x8*)(cb0 + T*64 + 32);
    b[3] = *(const bf16x8*)(cb1 + T*64 + 32);
  };
  auto mmf = [&](bf16x8 (&a)[2], bf16x8 (&b)[4]) {
    acc0 = __builtin_amdgcn_mfma_f32_16x16x32_bf16(a[0], b[0], acc0, 0, 0, 0);
    acc1 = __builtin_amdgcn_mfma_f32_16x16x32_bf16(a[0], b[1], acc1, 0, 0, 0);
    acc0 = __builtin_amdgcn_mfma_f32_16x16x32_bf16(a[1], b[2], acc0, 0, 0, 0);
    acc1 = __builtin_amdgcn_mfma_f32_16x16x32_bf16(a[1], b[3], acc1, 0, 0, 0);
  };

  bf16x8 pa[2], pb[4], qa[2], qb[4];
  ldf(pa, pb, 0);
  for (int t = 0; t < 40; t += 2) {
    ldf(qa, qb, t + 1);               // prefetch phase B while A computes
    mmf(pa, pb);
    if (t + 2 < 40) ldf(pa, pb, t + 2);
    mmf(qa, qb);
  }

  // ---- h-chain (K=128), B direct from L2; A via 4KB LDS h-tile ----
  auto writeH = [&](const f32x4& A0, const f32x4& A1, const float* bias) {
#pragma unroll
    for (int jj = 0; jj < 2; ++jj) {
      f32x4 av = jj ? A1 : A0;
      int col = wc + jj*16 + m16;
      float bv = bias[col];
#pragma unroll
      for (int reg = 0; reg < 4; ++reg) {
        int row = quad*4 + reg;
        int chunk = col >> 3;
        Hs[(row*16 + (chunk ^ row))*8 + (col & 7)] =
            f2b(fmaxf(av[reg] + bv, 0.f));
      }
    }
  };
  auto mm128 = [&](const u16* Wt, f32x4& o0, f32x4& o1) {
#pragma unroll
    for (int ks = 0; ks < 4; ++ks) {
      int cb = ks*4 + quad;
      bf16x8 a = *(const bf16x8*)&Hs[(m16*16 + (cb ^ m16))*8];
      bf16x8 bv0 = *(const bf16x8*)(Wt + (size_t)(wc      + m16)*128 + cb*8);
      bf16x8 bv1 = *(const bf16x8*)(Wt + (size_t)(wc + 16 + m16)*128 + cb*8);
      o0 = __builtin_amdgcn_mfma_f32_16x16x32_bf16(a, bv0, o0, 0, 0, 0);
      o1 = __builtin_amdgcn_mfma_f32_16x16x32_bf16(a, bv1, o1, 0, 0, 0);
    }
  };

  for (int s = tid; s < 1536; s += 256) sFw[s] = f2b(FW[s]);
  if (tid < 12) sFb[tid] = fb[tid];
  writeH(acc0, acc1, b0);          // h1 -> Hs
  __syncthreads();
  f32x4 c20 = {}, c21 = {};
  mm128(W1t, c20, c21);
  __syncthreads();                 // h1 reads done
  writeH(c20, c21, b1);            // h2 -> Hs
  __syncthreads();
  f32x4 c30 = {}, c31 = {};
  mm128(W2t, c30, c31);
  __syncthreads();                 // h2 reads done
  writeH(c30, c31, b2);            // h3 -> Hs
  __syncthreads();

  // h3 store (linear) + forecast accumulation
  {
    int row = tid >> 4, g = tid & 15;
    bf16x8 v = *(const bf16x8*)&Hs[(row*16 + (g ^ row))*8];
    *(bf16x8*)(h3 + (size_t)(r0 + row)*128 + g*8) = v;
  }
  if (tid < 192) {
    int row = tid / 12, t = tid - (tid/12)*12;
    float a = sFb[t];
#pragma unroll
    for (int chunk = 0; chunk < 16; ++chunk) {
      const u16* hp = &Hs[(row*16 + (chunk ^ row))*8];
#pragma unroll
      for (int jq = 0; jq < 8; ++jq)
        a = fmaf(b2f(hp[jq]), b2f(sFw[(chunk*8 + jq)*12 + t]), a);
    }
    f_acc[(size_t)(r0 + row)*12 + t] += a;
  }
}

// ---------------- k_back: straight-line back GEMM tile + epilogue ------------
// Round-6: R4 geometry (grid 207x20, 64r x 128c, K=128) but no staging at all:
// 24 direct fragment loads + 32 MFMA (addressing = R3's validated pattern),
// LDS only for the Cs epilogue (34 KB -> 4 blocks/CU). 4140 blocks give the
// TLP that hides L2 latency.
template<int FINAL>
__global__ __launch_bounds__(256, 4) void k_back(
    const u16* __restrict__ h3, const u16* __restrict__ BWt,
    const float* __restrict__ bbias, u16* __restrict__ xb,
    float* __restrict__ xf)
{
  __shared__ float Cs[64*132];     // 33.8 KB
  const int tid = threadIdx.x, wv = tid >> 6, lane = tid & 63;
  const int m16 = lane & 15, quad = lane >> 4;
  const int wr2 = (wv & 1) * 32, wc2 = (wv >> 1) * 64;
  const int gr0 = blockIdx.x * 64, n0 = blockIdx.y * 128;

  const u16* ab0 = h3 + (size_t)(gr0 + wr2 + m16)*128 + quad*8;
  const u16* ab1 = ab0 + 2048;     // +16 rows
  const u16* bbp = BWt + (size_t)(n0 + wc2 + m16)*128 + quad*8;
  float bb[4];
#pragma unroll
  for (int jj = 0; jj < 4; ++jj) bb[jj] = bbias[n0 + wc2 + jj*16 + m16];

  f32x4 bacc[2][4] = {};
#pragma unroll
  for (int ks = 0; ks < 4; ++ks) {
    bf16x8 a0 = *(const bf16x8*)(ab0 + ks*32);
    bf16x8 a1 = *(const bf16x8*)(ab1 + ks*32);
#pragma unroll
    for (int jj = 0; jj < 4; ++jj) {
      bf16x8 b = *(const bf16x8*)(bbp + (size_t)jj*2048 + ks*32);
      bacc[0][jj] = __builtin_amdgcn_mfma_f32_16x16x32_bf16(a0, b, bacc[0][jj], 0, 0, 0);
      bacc[1][jj] = __builtin_amdgcn_mfma_f32_16x16x32_bf16(a1, b, bacc[1][jj], 0, 0, 0);
    }
  }
#pragma unroll
  for (int mi = 0; mi < 2; ++mi)
#pragma unroll
    for (int jj = 0; jj < 4; ++jj) {
      int col = wc2 + jj*16 + m16;
#pragma unroll
      for (int reg = 0; reg < 4; ++reg) {
        int row = wr2 + mi*16 + quad*4 + reg;
        Cs[row*132 + col] = bacc[mi][jj][reg] + bb[jj];
      }
    }
  __syncthreads();
  if constexpr (!FINAL) {
    int row = tid >> 2, cq = tid & 3;
    u16* xp = xb + (size_t)(gr0 + row)*2560 + n0 + cq*32;
#pragma unroll
    for (int q = 0; q < 4; ++q) {
      bf16x8 old = *(const bf16x8*)(xp + q*8);
      u16 nv[8];
#pragma unroll
      for (int i = 0; i < 8; ++i)
        nv[i] = f2b(fmaxf(b2f((u16)old[i]) - Cs[row*132 + cq*32 + q*8 + i], 0.f));
      *(bf16x8*)(xp + q*8) = *(bf16x8*)nv;
    }
  } else {
    int p = tid >> 3, cg = tid & 7;
    int ra = 2*p, bn = (gr0 >> 1) + p;
    const u16* x0 = xb + (size_t)(gr0 + ra)*2560 + n0 + cg*16;
    const u16* x1 = x0 + 2560;
    float* op = xf + (size_t)bn*XSTRIDE + (size_t)(n0 + cg*16)*2;
#pragma unroll
    for (int q = 0; q < 2; ++q) {
      bf16x8 o0 = *(const bf16x8*)(x0 + q*8);
      bf16x8 o1 = *(const bf16x8*)(x1 + q*8);
#pragma unroll
      for (int i = 0; i < 8; i += 2) {
        int k = cg*16 + q*8 + i;
        float4 w;
        w.x = fmaxf(b2f((u16)o0[i])   - Cs[ra*132 + k],         0.f);
        w.y = fmaxf(b2f((u16)o1[i])   - Cs[(ra+1)*132 + k],     0.f);
        w.z = fmaxf(b2f((u16)o0[i+1]) - Cs[ra*132 + k + 1],     0.f);
        w.w = fmaxf(b2f((u16)o1[i+1]) - Cs[(ra+1)*132 + k + 1], 0.f);
        *(float4*)(op + (q*8 + i)*2) = w;
      }
    }
  }
}

// ---------------- finalize forecast ----------------
__global__ __launch_bounds__(256) void k_forecast(
    const float* __restrict__ f_acc, const float* __restrict__ level,
    const float* __restrict__ tgf, float* __restrict__ outf)
{
  int idx = blockIdx.x*256 + threadIdx.x;
  if (idx >= BN*24) return;
  int bn = idx / 24;
  int rem = idx - bn*24;
  int t = rem >> 1, c = rem & 1;
  float v = f_acc[bn*24 + c*12 + t];
  outf[idx] = v * level[bn*2 + c] * (1.f + tgf[bn*12 + t]);
}

extern "C" void kernel_launch(void* const* d_in, const int* in_sizes, int n_in,
                              void* d_out, int out_size, void* d_ws, size_t ws_size,
                              hipStream_t stream)
{
  const float* hist = (const float*)d_in[0];
  const float* tod  = (const float*)d_in[1];
  const float* emb  = (const float*)d_in[2];
  const float* tg1w = (const float*)d_in[3];
  const float* tg1b = (const float*)d_in[4];
  const float* tg2w = (const float*)d_in[5];
  const float* tg2b = (const float*)d_in[6];
  const float* tg3w = (const float*)d_in[7];
  const float* tg3b = (const float*)d_in[8];
  const float* fc0w = (const float*)d_in[9];
  const float* fc0b = (const float*)d_in[10];
  const float* fcw  = (const float*)d_in[11];
  const float* fcb  = (const float*)d_in[12];
  const float* forew= (const float*)d_in[13];
  const float* foreb= (const float*)d_in[14];
  const float* backw= (const float*)d_in[15];
  const float* backb= (const float*)d_in[16];

  char* w = (char*)d_ws;
  float* h_in  = (float*)w; w += 635904;     // 158976 f32
  float* level = (float*)w; w += 52992;      // 13248 f32
  float* tgf   = (float*)w; w += 317952;     // 79488 f32
  float* dp    = (float*)w; w += 171408;     // 42852 f32
  float* f_acc = (float*)w; w += 635904;     // 158976 f32
  u16* fc0wt   = (u16*)w;   w += 1966080;    // 3 x [128][2560]
  u16* fcwt    = (u16*)w;   w += 196608;     // 6 x [128][128]
  u16* backwt  = (u16*)w;   w += 1966080;    // 3 x [2560][128]
  u16* xb      = (u16*)w;   w += 67829760;   // 13248*2560 bf16
  u16* h3      = (u16*)w;   w += 3391488;    // 13248*128 bf16

  float* x    = (float*)d_out;                               // [bn][k][c] fp32
  float* outf = (float*)d_out + (size_t)BN*CONCATk*Cc;

  k_transp<<<dim3(40, 2, 3), 256, 0, stream>>>(fc0w, fc0wt, 2560, 128);
  k_transp<<<dim3(2, 2, 6), 256, 0, stream>>>(fcw, fcwt, 128, 128);
  k_transp<<<dim3(2, 40, 3), 256, 0, stream>>>(backw, backwt, 128, 2560);
  k_timegate<<<BN, 128, 0, stream>>>(hist, tod, emb, tg1w, tg1b, tg2w, tg2b,
                                     tg3w, tg3b, h_in, level, tgf, f_acc);
  k_dp<<<Nn, 256, 0, stream>>>(emb, dp);
  k_build_b<<<BN, 256, 0, stream>>>(h_in, level, dp, emb, xb);

  for (int i = 0; i < NBb; ++i) {
    const u16* W0t = fc0wt + (size_t)i*327680;
    const u16* W1t = fcwt + (size_t)(i*2+0)*16384;
    const u16* W2t = fcwt + (size_t)(i*2+1)*16384;
    const u16* BWt = backwt + (size_t)i*327680;
    k_fc<<<828, 256, 0, stream>>>(xb, W0t, fc0b + i*128, W1t, fcb + (i*2+0)*128,
                                  W2t, fcb + (i*2+1)*128, forew + (size_t)i*1536,
                                  foreb + i*12, f_acc, h3);
    if (i < NBb-1)
      k_back<0><<<dim3(207, 20), 256, 0, stream>>>(h3, BWt, backb + (size_t)i*2560,
                                                   xb, nullptr);
    else
      k_back<1><<<dim3(207, 20), 256, 0, stream>>>(h3, BWt, backb + (size_t)i*2560,
                                                   xb, x);
  }
  k_forecast<<<(BN*24 + 255)/256, 256, 0, stream>>>(f_acc, level, tgf, outf);
}

// Round 7
// 503.646 us; speedup vs baseline: 1.5904x; 1.5904x over previous
//
#include <hip/hip_runtime.h>
#include <math.h>

#define Bsz 32
#define Nn 207
#define Tt 12
#define Cc 2
#define HORr 12
#define DIDd 64
#define Hh 128
#define NBb 3
#define CONCATk 2560
#define BN (Bsz*Nn)           // 6624
#define ROWS (BN*Cc)          // 13248 = 414*32 = 207*64
#define XSTRIDE (CONCATk*Cc)  // 5120

typedef unsigned short u16;
typedef __attribute__((ext_vector_type(8))) short bf16x8;
typedef __attribute__((ext_vector_type(4))) float f32x4;

__device__ inline u16 f2b(float f) {
  unsigned u = __builtin_bit_cast(unsigned, f);
  u += 0x7fffu + ((u >> 16) & 1u);          // RNE
  return (u16)(u >> 16);
}
__device__ inline float b2f(u16 b) {
  unsigned u = ((unsigned)b) << 16;
  return __builtin_bit_cast(float, u);
}
__device__ inline void gld16(const void* g, void* l) {
  __builtin_amdgcn_global_load_lds((const __attribute__((address_space(1))) void*)g,
                                   (__attribute__((address_space(3))) void*)l, 16, 0, 0);
}

// ---------------- K1: time gates + h_in + level + zero f_acc ----------------
__global__ __launch_bounds__(128) void k_timegate(
    const float* __restrict__ hist, const float* __restrict__ tod,
    const float* __restrict__ emb,
    const float* __restrict__ w1, const float* __restrict__ b1,
    const float* __restrict__ w2, const float* __restrict__ b2,
    const float* __restrict__ w3, const float* __restrict__ b3,
    float* __restrict__ h_in, float* __restrict__ level,
    float* __restrict__ tgf, float* __restrict__ f_acc)
{
  int bn = blockIdx.x;
  int n = bn % Nn;
  __shared__ float s_in[76];
  __shared__ float s_tg[128];
  __shared__ float s_tgb[12];
  __shared__ float s_h[24];
  __shared__ float part[24][4];
  int tid = threadIdx.x;
  if (tid < 64) s_in[tid] = emb[n*64 + tid];
  else if (tid < 76) s_in[tid] = tod[bn*12 + (tid - 64)];
  __syncthreads();
  float acc = b1[tid];
#pragma unroll 4
  for (int k = 0; k < 76; ++k) acc = fmaf(s_in[k], w1[k*128 + tid], acc);
  s_tg[tid] = fmaxf(acc, 0.f);
  __syncthreads();
  if (tid < 96) {
    int j = tid >> 2, p = tid & 3;
    int jj = (j < 12) ? j : j - 12;
    const float* w = (j < 12) ? w2 : w3;
    float a = 0.f;
#pragma unroll 8
    for (int k = p*32; k < p*32 + 32; ++k) a = fmaf(s_tg[k], w[k*12 + jj], a);
    part[j][p] = a;
  }
  __syncthreads();
  if (tid < 24) {
    int jj = (tid < 12) ? tid : tid - 12;
    float a = ((tid < 12) ? b2[jj] : b3[jj])
            + part[tid][0] + part[tid][1] + part[tid][2] + part[tid][3];
    if (tid < 12) tgf[bn*12 + jj] = a;
    else s_tgb[jj] = a;
  }
  __syncthreads();
  if (tid < 24) {
    int t = tid >> 1;
    float v = hist[bn*24 + tid] / (1.f + s_tgb[t]);
    h_in[bn*24 + tid] = v;
    s_h[tid] = v;
    f_acc[bn*24 + tid] = 0.f;
  }
  __syncthreads();
  if (tid < 2) {
    float m = s_h[tid];
    for (int t = 1; t < 12; ++t) m = fmaxf(m, s_h[t*2 + tid]);
    level[bn*2 + tid] = m;
  }
}

// ---------------- K2: dp[n,m] = exp(10 * <emb_n, emb_m>) ----------------
__global__ __launch_bounds__(256) void k_dp(const float* __restrict__ emb,
                                            float* __restrict__ dp)
{
  int n = blockIdx.x;
  __shared__ float e[64];
  int tid = threadIdx.x;
  if (tid < 64) e[tid] = emb[n*64 + tid];
  __syncthreads();
  if (tid < Nn) {
    float a = 0.f;
#pragma unroll 8
    for (int k = 0; k < 64; ++k) a = fmaf(e[k], emb[tid*64 + k], a);
    dp[n*Nn + tid] = expf(10.f * a);
  }
}

// ---------------- weight transpose+convert: fp32 [K][N] -> bf16 [N][K] -------
__global__ __launch_bounds__(256) void k_transp(
    const float* __restrict__ src, u16* __restrict__ dst, int K, int N)
{
  int k0 = blockIdx.x*64, n0 = blockIdx.y*64;
  size_t mo = (size_t)blockIdx.z * K * N;
  src += mo; dst += mo;
  __shared__ u16 Ts[64][72];
  int tid = threadIdx.x;
#pragma unroll
  for (int it = 0; it < 4; ++it) {
    int idx = it*256 + tid;
    int r = idx >> 4, q = idx & 15;
    float4 v = *(const float4*)(src + (size_t)(k0 + r)*N + n0 + q*4);
    Ts[r][q*4+0] = f2b(v.x);
    Ts[r][q*4+1] = f2b(v.y);
    Ts[r][q*4+2] = f2b(v.z);
    Ts[r][q*4+3] = f2b(v.w);
  }
  __syncthreads();
#pragma unroll
  for (int it = 0; it < 2; ++it) {
    int idx = it*256 + tid;
    int nl = idx >> 3, kq = idx & 7;
    u16 o[8];
#pragma unroll
    for (int j = 0; j < 8; ++j) o[j] = Ts[kq*8 + j][nl];
    *(bf16x8*)(dst + (size_t)(n0 + nl)*K + k0 + kq*8) = *(bf16x8*)o;
  }
}

// ---------------- build xb bf16, row-major [r=bn*2+c][k] ---------------------
__global__ __launch_bounds__(256) void k_build_b(
    const float* __restrict__ h_in, const float* __restrict__ level,
    const float* __restrict__ dp, const float* __restrict__ emb,
    u16* __restrict__ xb)
{
  int bn = blockIdx.x;
  int b = bn / Nn, n = bn - b*Nn;
  __shared__ float s_dp[Nn];
  __shared__ __attribute__((aligned(16))) u16 row[2][2560];
  int tid = threadIdx.x;
  for (int m = tid; m < Nn; m += 256) s_dp[m] = dp[n*Nn + m];
  float lev0 = level[bn*2], lev1 = level[bn*2+1];
  float inv0 = 1.f/(lev0+1e-8f), inv1 = 1.f/(lev1+1e-8f);
  __syncthreads();
  if (tid < Nn) {
    int m = tid;
    float dpm = s_dp[m];
    const float2* hp = (const float2*)(h_in + (size_t)(b*Nn + m)*24);
#pragma unroll
    for (int t = 0; t < 12; ++t) {
      float2 v = hp[t];
      row[0][12 + m*12 + t] = f2b(fmaxf((v.x*dpm - lev0)*inv0, 0.f));
      row[1][12 + m*12 + t] = f2b(fmaxf((v.y*dpm - lev1)*inv1, 0.f));
    }
  } else if (tid < 219) {            // history (12 t, both c)
    int t = tid - 207;
    float2 v = *(const float2*)(h_in + (size_t)bn*24 + t*2);
    row[0][t] = f2b(v.x*inv0);
    row[1][t] = f2b(v.y*inv1);
  } else if (tid < 251) {            // emb: 32 threads x 2 elems
    int e = (tid - 219)*2;
    float2 ev = *(const float2*)(emb + n*64 + e);
    u16 a = f2b(ev.x), bq = f2b(ev.y);
    row[0][2496+e] = a; row[0][2497+e] = bq;
    row[1][2496+e] = a; row[1][2497+e] = bq;
  }
  __syncthreads();
  for (int s = tid; s < 640; s += 256) {
    int c = s >= 320, ks = s - c*320;
    *(bf16x8*)(xb + (size_t)(bn*2 + c)*2560 + ks*8) = *(const bf16x8*)&row[c][ks*8];
  }
}

// ---------------- k_fc0: fc0 split-K2, writes bf16 partials ------------------
// Round-7: R4's proven staged pipeline, but grid (414,2): blockIdx.y = K-half.
// Same total staged bytes as R4's fc0 (828 x 400KB), but 40KB LDS + 828 blocks
// -> ~3.2 co-resident chains/CU (R1 measured 38 GB/s/CU at this co-residency
// vs 25 at 2/CU). Partials pc[kh][row][128] in bf16.
__global__ __launch_bounds__(256, 3) void k_fc0(
    const u16* __restrict__ xb, const u16* __restrict__ W0t,
    u16* __restrict__ pc)
{
  __shared__ __attribute__((aligned(16))) u16 As[2*2048];   //  8 KB A dbuf (32r x 64k)
  __shared__ __attribute__((aligned(16))) u16 Bs[2*8192];   // 32 KB B dbuf (128c x 64k)
  const int tid = threadIdx.x, wv = tid >> 6, lane = tid & 63;
  const int m16 = lane & 15, quad = lane >> 4;
  const int wr = (wv & 1) * 16, wc = (wv >> 1) * 64;
  const int r0 = blockIdx.x * 32;
  const int kh = blockIdx.y, k0 = kh * 1280;

  const int s_row = tid >> 3, s_ch = tid & 7;
  const u16* a_src = xb + (size_t)(r0 + s_row)*2560 + k0 + (s_ch ^ (s_row & 7))*8;
  u16* a_dst = As + wv*512;
  const u16* b_src[4];
#pragma unroll
  for (int it = 0; it < 4; ++it) {
    int slot = it*256 + tid, nl = slot >> 3, g = (slot & 7) ^ (nl & 7);
    b_src[it] = W0t + (size_t)nl*2560 + k0 + g*8;
  }
  u16* b_dst = Bs + wv*512;
  auto issueF = [&](int t, int buf) {
    gld16(a_src + t*64, a_dst + buf*2048);
#pragma unroll
    for (int it = 0; it < 4; ++it)
      gld16(b_src[it] + t*64, b_dst + buf*8192 + it*2048);
  };

  issueF(0, 0);
  f32x4 acc[4] = {};
  for (int j = 0; j < 20; ++j) {
    const int buf = j & 1;
    asm volatile("s_waitcnt vmcnt(0)" ::: "memory");
    __builtin_amdgcn_sched_barrier(0);
    __builtin_amdgcn_s_barrier();
    __builtin_amdgcn_sched_barrier(0);
    if (j < 19) issueF(j + 1, buf ^ 1);
    const u16* Ab = As + buf*2048;
    const u16* Bb = Bs + buf*8192;
#pragma unroll
    for (int ks = 0; ks < 2; ++ks) {
      int cb = ks*4 + quad;
      int ar = wr + m16;
      bf16x8 a = *(const bf16x8*)&Ab[(ar*8 + (cb ^ (ar & 7)))*8];
#pragma unroll
      for (int jj = 0; jj < 4; ++jj) {
        int nl = wc + jj*16 + m16;
        bf16x8 b = *(const bf16x8*)&Bb[(nl*8 + (cb ^ (nl & 7)))*8];
        acc[jj] = __builtin_amdgcn_mfma_f32_16x16x32_bf16(a, b, acc[jj], 0, 0, 0);
      }
    }
  }

  u16* pcH = pc + (size_t)kh*ROWS*128;
#pragma unroll
  for (int jj = 0; jj < 4; ++jj) {
    int col = wc + jj*16 + m16;
#pragma unroll
    for (int reg = 0; reg < 4; ++reg) {
      int row = r0 + wr + quad*4 + reg;
      pcH[(size_t)row*128 + col] = f2b(acc[jj][reg]);
    }
  }
}

// ---------------- k_hchain: h1 from partials -> h2 -> h3 + fore --------------
// grid 414 (32-row tiles), 256 thr / 4 waves; R4's h-chain verbatim, with the
// fc0 result reconstructed as h1 = relu(p0 + p1 + b0). ~43KB LDS.
__global__ __launch_bounds__(256, 3) void k_hchain(
    const u16* __restrict__ pc, const float* __restrict__ b0,
    const u16* __restrict__ W1t, const float* __restrict__ b1,
    const u16* __restrict__ W2t, const float* __restrict__ b2,
    const float* __restrict__ FW, const float* __restrict__ fb,
    float* __restrict__ f_acc, u16* __restrict__ h3)
{
  __shared__ __attribute__((aligned(16))) u16 Bs[16384];    // 32 KB W1/W2
  __shared__ __attribute__((aligned(16))) u16 Hs[4096];     //  8 KB h tile
  __shared__ __attribute__((aligned(16))) u16 sFw[1536];    //  3 KB FW bf16
  __shared__ float sFb[12];
  const int tid = threadIdx.x, wv = tid >> 6, lane = tid & 63;
  const int m16 = lane & 15, quad = lane >> 4;
  const int wr = (wv & 1) * 16, wc = (wv >> 1) * 64;
  const int r0 = blockIdx.x * 32;

  auto stageW = [&](const u16* W) {
#pragma unroll
    for (int it = 0; it < 8; ++it) {
      int slot = it*256 + tid, nl = slot >> 4, g = (slot & 15) ^ (nl & 15);
      gld16(W + (size_t)nl*128 + g*8, Bs + it*2048 + wv*512);
    }
  };
  auto writeH = [&](const f32x4* ac, const float* bias) {
#pragma unroll
    for (int jj = 0; jj < 4; ++jj) {
      int col = wc + jj*16 + m16;
      float bv = bias[col];
#pragma unroll
      for (int reg = 0; reg < 4; ++reg) {
        int row = wr + quad*4 + reg;
        int chunk = col >> 3;
        Hs[(row*16 + (chunk ^ (row & 15)))*8 + (col & 7)] =
            f2b(fmaxf(ac[jj][reg] + bv, 0.f));
      }
    }
  };
  auto mm128 = [&](f32x4* ac) {
#pragma unroll
    for (int ks = 0; ks < 4; ++ks) {
      int cb = ks*4 + quad;
      int ar = wr + m16;
      bf16x8 a = *(const bf16x8*)&Hs[(ar*16 + (cb ^ (ar & 15)))*8];
#pragma unroll
      for (int jj = 0; jj < 4; ++jj) {
        int nl = wc + jj*16 + m16;
        bf16x8 b = *(const bf16x8*)&Bs[(nl*16 + (cb ^ (nl & 15)))*8];
        ac[jj] = __builtin_amdgcn_mfma_f32_16x16x32_bf16(a, b, ac[jj], 0, 0, 0);
      }
    }
  };

  stageW(W1t);                     // prefetch W1 under the h1 build
  // h1 = relu(p0 + p1 + b0): thread -> (row, 16-col group)
  {
    int row = tid >> 3, cg = tid & 7;
    const u16* p0 = pc + (size_t)(r0 + row)*128 + cg*16;
    const u16* p1 = p0 + (size_t)ROWS*128;
#pragma unroll
    for (int q = 0; q < 4; ++q) {
      float4 bb = *(const float4*)(b0 + cg*16 + q*4);
#pragma unroll
      for (int i = 0; i < 4; ++i) {
        int col = cg*16 + q*4 + i;
        float v = fmaxf(b2f(p0[q*4+i]) + b2f(p1[q*4+i]) + ((const float*)&bb)[i], 0.f);
        int chunk = col >> 3;
        Hs[(row*16 + (chunk ^ (row & 15)))*8 + (col & 7)] = f2b(v);
      }
    }
  }
  for (int s = tid; s < 1536; s += 256) sFw[s] = f2b(FW[s]);
  if (tid < 12) sFb[tid] = fb[tid];
  __syncthreads();                 // Hs(h1) ready, W1 staged (sync drains vmem)

  f32x4 acc2[4] = {};
  mm128(acc2);
  __syncthreads();
  stageW(W2t);
  writeH(acc2, b1);                // h2 -> Hs
  __syncthreads();

  f32x4 acc3[4] = {};
  mm128(acc3);
  __syncthreads();
  writeH(acc3, b2);                // h3 -> Hs
  __syncthreads();

  // h3 store (linear) + forecast accumulation
  for (int s = tid; s < 512; s += 256) {
    int row = s >> 4, g = s & 15;
    bf16x8 v = *(const bf16x8*)&Hs[(row*16 + (g ^ (row & 15)))*8];
    *(bf16x8*)(h3 + (size_t)(r0 + row)*128 + g*8) = v;
  }
  for (int o = tid; o < 384; o += 256) {
    int row = o / 12, t = o - (o/12)*12;
    float a = sFb[t];
#pragma unroll
    for (int chunk = 0; chunk < 16; ++chunk) {
      const u16* hp = &Hs[(row*16 + (chunk ^ (row & 15)))*8];
#pragma unroll
      for (int jq = 0; jq < 8; ++jq)
        a = fmaf(b2f(hp[jq]), b2f(sFw[(chunk*8 + jq)*12 + t]), a);
    }
    f_acc[(size_t)(r0 + row)*12 + t] += a;
  }
}

// ---------------- k_back: single-shot back GEMM tile + RMW epilogue ----------
// R4 verbatim: grid (207,20), 64r x 128c, K=128, 48KB LDS, 3 blk/CU.
template<int FINAL>
__global__ __launch_bounds__(256, 3) void k_back(
    const u16* __restrict__ h3, const u16* __restrict__ BWt,
    const float* __restrict__ bbias, u16* __restrict__ xb,
    float* __restrict__ xf)
{
  __shared__ __attribute__((aligned(16))) u16 Sm[24576];   // 48KB; aliased as Cs
  __shared__ float sBb[128];
  const int tid = threadIdx.x, wv = tid >> 6, lane = tid & 63;
  const int m16 = lane & 15, quad = lane >> 4;
  const int wr2 = (wv & 1) * 32, wc2 = (wv >> 1) * 64;
  const int gr0 = blockIdx.x * 64, n0 = blockIdx.y * 128;
  u16* Asl = Sm;             // h3 tile: 64 rows x 16 granules
  u16* Bsl = Sm + 8192;      // BW tile: 128 cols x 16 granules

#pragma unroll
  for (int it = 0; it < 4; ++it) {
    int slot = it*256 + tid, row = slot >> 4, g = (slot & 15) ^ (row & 15);
    gld16(h3 + (size_t)(gr0 + row)*128 + g*8, Asl + it*2048 + wv*512);
  }
#pragma unroll
  for (int it = 0; it < 8; ++it) {
    int slot = it*256 + tid, nl = slot >> 4, g = (slot & 15) ^ (nl & 15);
    gld16(BWt + (size_t)(n0 + nl)*128 + g*8, Bsl + it*2048 + wv*512);
  }
  if (tid < 128) sBb[tid] = bbias[n0 + tid];
  __syncthreads();

  f32x4 bacc[2][4] = {};
#pragma unroll
  for (int ks = 0; ks < 4; ++ks) {
    int cb = ks*4 + quad;
    int ar0 = wr2 + m16, ar1 = wr2 + 16 + m16;
    bf16x8 a0 = *(const bf16x8*)&Asl[(ar0*16 + (cb ^ (ar0 & 15)))*8];
    bf16x8 a1 = *(const bf16x8*)&Asl[(ar1*16 + (cb ^ (ar1 & 15)))*8];
#pragma unroll
    for (int jj = 0; jj < 4; ++jj) {
      int nl = wc2 + jj*16 + m16;
      bf16x8 b = *(const bf16x8*)&Bsl[(nl*16 + (cb ^ (nl & 15)))*8];
      bacc[0][jj] = __builtin_amdgcn_mfma_f32_16x16x32_bf16(a0, b, bacc[0][jj], 0, 0, 0);
      bacc[1][jj] = __builtin_amdgcn_mfma_f32_16x16x32_bf16(a1, b, bacc[1][jj], 0, 0, 0);
    }
  }
  __syncthreads();                 // staging reads done; alias Cs
  float* Cs = (float*)Sm;          // [64][132]
#pragma unroll
  for (int mi = 0; mi < 2; ++mi)
#pragma unroll
    for (int jj = 0; jj < 4; ++jj) {
      int col = wc2 + jj*16 + m16;
      float bb = sBb[col];
#pragma unroll
      for (int reg = 0; reg < 4; ++reg) {
        int row = wr2 + mi*16 + quad*4 + reg;
        Cs[row*132 + col] = bacc[mi][jj][reg] + bb;
      }
    }
  __syncthreads();
  if constexpr (!FINAL) {
    int row = tid >> 2, cq = tid & 3;
    u16* xp = xb + (size_t)(gr0 + row)*2560 + n0 + cq*32;
#pragma unroll
    for (int q = 0; q < 4; ++q) {
      bf16x8 old = *(const bf16x8*)(xp + q*8);
      u16 nv[8];
#pragma unroll
      for (int i = 0; i < 8; ++i)
        nv[i] = f2b(fmaxf(b2f((u16)old[i]) - Cs[row*132 + cq*32 + q*8 + i], 0.f));
      *(bf16x8*)(xp + q*8) = *(bf16x8*)nv;
    }
  } else {
    int p = tid >> 3, cg = tid & 7;
    int ra = 2*p, bn = (gr0 >> 1) + p;
    const u16* x0 = xb + (size_t)(gr0 + ra)*2560 + n0 + cg*16;
    const u16* x1 = x0 + 2560;
    float* op = xf + (size_t)bn*XSTRIDE + (size_t)(n0 + cg*16)*2;
#pragma unroll
    for (int q = 0; q < 2; ++q) {
      bf16x8 o0 = *(const bf16x8*)(x0 + q*8);
      bf16x8 o1 = *(const bf16x8*)(x1 + q*8);
#pragma unroll
      for (int i = 0; i < 8; i += 2) {
        int k = cg*16 + q*8 + i;
        float4 w;
        w.x = fmaxf(b2f((u16)o0[i])   - Cs[ra*132 + k],         0.f);
        w.y = fmaxf(b2f((u16)o1[i])   - Cs[(ra+1)*132 + k],     0.f);
        w.z = fmaxf(b2f((u16)o0[i+1]) - Cs[ra*132 + k + 1],     0.f);
        w.w = fmaxf(b2f((u16)o1[i+1]) - Cs[(ra+1)*132 + k + 1], 0.f);
        *(float4*)(op + (q*8 + i)*2) = w;
      }
    }
  }
}

// ---------------- finalize forecast ----------------
__global__ __launch_bounds__(256) void k_forecast(
    const float* __restrict__ f_acc, const float* __restrict__ level,
    const float* __restrict__ tgf, float* __restrict__ outf)
{
  int idx = blockIdx.x*256 + threadIdx.x;
  if (idx >= BN*24) return;
  int bn = idx / 24;
  int rem = idx - bn*24;
  int t = rem >> 1, c = rem & 1;
  float v = f_acc[bn*24 + c*12 + t];
  outf[idx] = v * level[bn*2 + c] * (1.f + tgf[bn*12 + t]);
}

extern "C" void kernel_launch(void* const* d_in, const int* in_sizes, int n_in,
                              void* d_out, int out_size, void* d_ws, size_t ws_size,
                              hipStream_t stream)
{
  const float* hist = (const float*)d_in[0];
  const float* tod  = (const float*)d_in[1];
  const float* emb  = (const float*)d_in[2];
  const float* tg1w = (const float*)d_in[3];
  const float* tg1b = (const float*)d_in[4];
  const float* tg2w = (const float*)d_in[5];
  const float* tg2b = (const float*)d_in[6];
  const float* tg3w = (const float*)d_in[7];
  const float* tg3b = (const float*)d_in[8];
  const float* fc0w = (const float*)d_in[9];
  const float* fc0b = (const float*)d_in[10];
  const float* fcw  = (const float*)d_in[11];
  const float* fcb  = (const float*)d_in[12];
  const float* forew= (const float*)d_in[13];
  const float* foreb= (const float*)d_in[14];
  const float* backw= (const float*)d_in[15];
  const float* backb= (const float*)d_in[16];

  char* w = (char*)d_ws;
  float* h_in  = (float*)w; w += 635904;     // 158976 f32
  float* level = (float*)w; w += 52992;      // 13248 f32
  float* tgf   = (float*)w; w += 317952;     // 79488 f32
  float* dp    = (float*)w; w += 171408;     // 42852 f32
  float* f_acc = (float*)w; w += 635904;     // 158976 f32
  u16* fc0wt   = (u16*)w;   w += 1966080;    // 3 x [128][2560]
  u16* fcwt    = (u16*)w;   w += 196608;     // 6 x [128][128]
  u16* backwt  = (u16*)w;   w += 1966080;    // 3 x [2560][128]
  u16* xb      = (u16*)w;   w += 67829760;   // 13248*2560 bf16
  u16* h3      = (u16*)w;   w += 3391488;    // 13248*128 bf16
  u16* pc      = (u16*)w;   w += 6782976;    // 2 x 13248*128 bf16 partials

  float* x    = (float*)d_out;                               // [bn][k][c] fp32
  float* outf = (float*)d_out + (size_t)BN*CONCATk*Cc;

  k_transp<<<dim3(40, 2, 3), 256, 0, stream>>>(fc0w, fc0wt, 2560, 128);
  k_transp<<<dim3(2, 2, 6), 256, 0, stream>>>(fcw, fcwt, 128, 128);
  k_transp<<<dim3(2, 40, 3), 256, 0, stream>>>(backw, backwt, 128, 2560);
  k_timegate<<<BN, 128, 0, stream>>>(hist, tod, emb, tg1w, tg1b, tg2w, tg2b,
                                     tg3w, tg3b, h_in, level, tgf, f_acc);
  k_dp<<<Nn, 256, 0, stream>>>(emb, dp);
  k_build_b<<<BN, 256, 0, stream>>>(h_in, level, dp, emb, xb);

  for (int i = 0; i < NBb; ++i) {
    const u16* W0t = fc0wt + (size_t)i*327680;
    const u16* W1t = fcwt + (size_t)(i*2+0)*16384;
    const u16* W2t = fcwt + (size_t)(i*2+1)*16384;
    const u16* BWt = backwt + (size_t)i*327680;
    k_fc0<<<dim3(414, 2), 256, 0, stream>>>(xb, W0t, pc);
    k_hchain<<<414, 256, 0, stream>>>(pc, fc0b + i*128, W1t, fcb + (i*2+0)*128,
                                      W2t, fcb + (i*2+1)*128,
                                      forew + (size_t)i*1536, foreb + i*12,
                                      f_acc, h3);
    if (i < NBb-1)
      k_back<0><<<dim3(207, 20), 256, 0, stream>>>(h3, BWt, backb + (size_t)i*2560,
                                                   xb, nullptr);
    else
      k_back<1><<<dim3(207, 20), 256, 0, stream>>>(h3, BWt, backb + (size_t)i*2560,
                                                   xb, x);
  }
  k_forecast<<<(BN*24 + 255)/256, 256, 0, stream>>>(f_acc, level, tgf, outf);
}

// Round 8
// 478.880 us; speedup vs baseline: 1.6726x; 1.0517x over previous
//
#include <hip/hip_runtime.h>
#include <math.h>

#define Bsz 32
#define Nn 207
#define Tt 12
#define Cc 2
#define HORr 12
#define DIDd 64
#define Hh 128
#define NBb 3
#define CONCATk 2560
#define BN (Bsz*Nn)           // 6624
#define ROWS (BN*Cc)          // 13248 = 414*32 = 69*192
#define XSTRIDE (CONCATk*Cc)  // 5120

typedef unsigned short u16;
typedef __attribute__((ext_vector_type(8))) short bf16x8;
typedef __attribute__((ext_vector_type(4))) float f32x4;

__device__ inline u16 f2b(float f) {
  unsigned u = __builtin_bit_cast(unsigned, f);
  u += 0x7fffu + ((u >> 16) & 1u);          // RNE
  return (u16)(u >> 16);
}
__device__ inline float b2f(u16 b) {
  unsigned u = ((unsigned)b) << 16;
  return __builtin_bit_cast(float, u);
}
__device__ inline void gld16(const void* g, void* l) {
  __builtin_amdgcn_global_load_lds((const __attribute__((address_space(1))) void*)g,
                                   (__attribute__((address_space(3))) void*)l, 16, 0, 0);
}

// ---------------- K1: time gates + h_in + level + zero f_acc ----------------
__global__ __launch_bounds__(128) void k_timegate(
    const float* __restrict__ hist, const float* __restrict__ tod,
    const float* __restrict__ emb,
    const float* __restrict__ w1, const float* __restrict__ b1,
    const float* __restrict__ w2, const float* __restrict__ b2,
    const float* __restrict__ w3, const float* __restrict__ b3,
    float* __restrict__ h_in, float* __restrict__ level,
    float* __restrict__ tgf, float* __restrict__ f_acc)
{
  int bn = blockIdx.x;
  int n = bn % Nn;
  __shared__ float s_in[76];
  __shared__ float s_tg[128];
  __shared__ float s_tgb[12];
  __shared__ float s_h[24];
  __shared__ float part[24][4];
  int tid = threadIdx.x;
  if (tid < 64) s_in[tid] = emb[n*64 + tid];
  else if (tid < 76) s_in[tid] = tod[bn*12 + (tid - 64)];
  __syncthreads();
  float acc = b1[tid];
#pragma unroll 4
  for (int k = 0; k < 76; ++k) acc = fmaf(s_in[k], w1[k*128 + tid], acc);
  s_tg[tid] = fmaxf(acc, 0.f);
  __syncthreads();
  if (tid < 96) {
    int j = tid >> 2, p = tid & 3;
    int jj = (j < 12) ? j : j - 12;
    const float* w = (j < 12) ? w2 : w3;
    float a = 0.f;
#pragma unroll 8
    for (int k = p*32; k < p*32 + 32; ++k) a = fmaf(s_tg[k], w[k*12 + jj], a);
    part[j][p] = a;
  }
  __syncthreads();
  if (tid < 24) {
    int jj = (tid < 12) ? tid : tid - 12;
    float a = ((tid < 12) ? b2[jj] : b3[jj])
            + part[tid][0] + part[tid][1] + part[tid][2] + part[tid][3];
    if (tid < 12) tgf[bn*12 + jj] = a;
    else s_tgb[jj] = a;
  }
  __syncthreads();
  if (tid < 24) {
    int t = tid >> 1;
    float v = hist[bn*24 + tid] / (1.f + s_tgb[t]);
    h_in[bn*24 + tid] = v;
    s_h[tid] = v;
    f_acc[bn*24 + tid] = 0.f;
  }
  __syncthreads();
  if (tid < 2) {
    float m = s_h[tid];
    for (int t = 1; t < 12; ++t) m = fmaxf(m, s_h[t*2 + tid]);
    level[bn*2 + tid] = m;
  }
}

// ---------------- K2: dp[n,m] = exp(10 * <emb_n, emb_m>) ----------------
__global__ __launch_bounds__(256) void k_dp(const float* __restrict__ emb,
                                            float* __restrict__ dp)
{
  int n = blockIdx.x;
  __shared__ float e[64];
  int tid = threadIdx.x;
  if (tid < 64) e[tid] = emb[n*64 + tid];
  __syncthreads();
  if (tid < Nn) {
    float a = 0.f;
#pragma unroll 8
    for (int k = 0; k < 64; ++k) a = fmaf(e[k], emb[tid*64 + k], a);
    dp[n*Nn + tid] = expf(10.f * a);
  }
}

// ---------------- weight transpose+convert: fp32 [K][N] -> bf16 [N][K] -------
__global__ __launch_bounds__(256) void k_transp(
    const float* __restrict__ src, u16* __restrict__ dst, int K, int N)
{
  int k0 = blockIdx.x*64, n0 = blockIdx.y*64;
  size_t mo = (size_t)blockIdx.z * K * N;
  src += mo; dst += mo;
  __shared__ u16 Ts[64][72];
  int tid = threadIdx.x;
#pragma unroll
  for (int it = 0; it < 4; ++it) {
    int idx = it*256 + tid;
    int r = idx >> 4, q = idx & 15;
    float4 v = *(const float4*)(src + (size_t)(k0 + r)*N + n0 + q*4);
    Ts[r][q*4+0] = f2b(v.x);
    Ts[r][q*4+1] = f2b(v.y);
    Ts[r][q*4+2] = f2b(v.z);
    Ts[r][q*4+3] = f2b(v.w);
  }
  __syncthreads();
#pragma unroll
  for (int it = 0; it < 2; ++it) {
    int idx = it*256 + tid;
    int nl = idx >> 3, kq = idx & 7;
    u16 o[8];
#pragma unroll
    for (int j = 0; j < 8; ++j) o[j] = Ts[kq*8 + j][nl];
    *(bf16x8*)(dst + (size_t)(n0 + nl)*K + k0 + kq*8) = *(bf16x8*)o;
  }
}

// ---------------- build xb bf16, row-major [r=bn*2+c][k] ---------------------
__global__ __launch_bounds__(256) void k_build_b(
    const float* __restrict__ h_in, const float* __restrict__ level,
    const float* __restrict__ dp, const float* __restrict__ emb,
    u16* __restrict__ xb)
{
  int bn = blockIdx.x;
  int b = bn / Nn, n = bn - b*Nn;
  __shared__ float s_dp[Nn];
  __shared__ __attribute__((aligned(16))) u16 row[2][2560];
  int tid = threadIdx.x;
  for (int m = tid; m < Nn; m += 256) s_dp[m] = dp[n*Nn + m];
  float lev0 = level[bn*2], lev1 = level[bn*2+1];
  float inv0 = 1.f/(lev0+1e-8f), inv1 = 1.f/(lev1+1e-8f);
  __syncthreads();
  if (tid < Nn) {
    int m = tid;
    float dpm = s_dp[m];
    const float2* hp = (const float2*)(h_in + (size_t)(b*Nn + m)*24);
#pragma unroll
    for (int t = 0; t < 12; ++t) {
      float2 v = hp[t];
      row[0][12 + m*12 + t] = f2b(fmaxf((v.x*dpm - lev0)*inv0, 0.f));
      row[1][12 + m*12 + t] = f2b(fmaxf((v.y*dpm - lev1)*inv1, 0.f));
    }
  } else if (tid < 219) {            // history (12 t, both c)
    int t = tid - 207;
    float2 v = *(const float2*)(h_in + (size_t)bn*24 + t*2);
    row[0][t] = f2b(v.x*inv0);
    row[1][t] = f2b(v.y*inv1);
  } else if (tid < 251) {            // emb: 32 threads x 2 elems
    int e = (tid - 219)*2;
    float2 ev = *(const float2*)(emb + n*64 + e);
    u16 a = f2b(ev.x), bq = f2b(ev.y);
    row[0][2496+e] = a; row[0][2497+e] = bq;
    row[1][2496+e] = a; row[1][2497+e] = bq;
  }
  __syncthreads();
  for (int s = tid; s < 640; s += 256) {
    int c = s >= 320, ks = s - c*320;
    *(bf16x8*)(xb + (size_t)(bn*2 + c)*2560 + ks*8) = *(const bf16x8*)&row[c][ks*8];
  }
}

// ---------------- k_fc: fc0 -> h1 -> h2 -> h3 + fore; writes h3 --------------
// R4 verbatim (best measured): grid 414 (32-row tiles), 256 thr / 4 waves,
// 51KB LDS, 2-buf gld16 pipeline, one barrier per K-step.
__global__ __launch_bounds__(256, 3) void k_fc(
    const u16* __restrict__ xb,
    const u16* __restrict__ W0t, const float* __restrict__ b0,
    const u16* __restrict__ W1t, const float* __restrict__ b1,
    const u16* __restrict__ W2t, const float* __restrict__ b2,
    const float* __restrict__ FW, const float* __restrict__ fb,
    float* __restrict__ f_acc, u16* __restrict__ h3)
{
  __shared__ __attribute__((aligned(16))) u16 As[2*2048];   //  8 KB A dbuf
  __shared__ __attribute__((aligned(16))) u16 Bs[2*8192];   // 32 KB B dbuf / W1,W2
  __shared__ __attribute__((aligned(16))) u16 Hs[4096];     //  8 KB h tile
  __shared__ __attribute__((aligned(16))) u16 sFw[1536];    //  3 KB FW bf16
  __shared__ float sFb[12];
  const int tid = threadIdx.x, wv = tid >> 6, lane = tid & 63;
  const int m16 = lane & 15, quad = lane >> 4;
  const int wr = (wv & 1) * 16, wc = (wv >> 1) * 64;
  const int r0 = blockIdx.x * 32;

  const int s_row = tid >> 3, s_ch = tid & 7;
  const u16* a_src = xb + (size_t)(r0 + s_row)*2560 + (s_ch ^ (s_row & 7))*8;
  u16* a_dst = As + wv*512;
  const u16* b_src[4];
#pragma unroll
  for (int it = 0; it < 4; ++it) {
    int slot = it*256 + tid, nl = slot >> 3, g = (slot & 7) ^ (nl & 7);
    b_src[it] = W0t + (size_t)nl*2560 + g*8;
  }
  u16* b_dst = Bs + wv*512;
  auto issueF = [&](int t, int buf) {
    gld16(a_src + t*64, a_dst + buf*2048);
#pragma unroll
    for (int it = 0; it < 4; ++it)
      gld16(b_src[it] + t*64, b_dst + buf*8192 + it*2048);
  };

  issueF(0, 0);
  f32x4 acc[4] = {};
  for (int j = 0; j < 40; ++j) {
    const int buf = j & 1;
    asm volatile("s_waitcnt vmcnt(0)" ::: "memory");
    __builtin_amdgcn_sched_barrier(0);
    __builtin_amdgcn_s_barrier();
    __builtin_amdgcn_sched_barrier(0);
    if (j < 39) issueF(j + 1, buf ^ 1);
    const u16* Ab = As + buf*2048;
    const u16* Bb = Bs + buf*8192;
#pragma unroll
    for (int ks = 0; ks < 2; ++ks) {
      int cb = ks*4 + quad;
      int ar = wr + m16;
      bf16x8 a = *(const bf16x8*)&Ab[(ar*8 + (cb ^ (ar & 7)))*8];
#pragma unroll
      for (int jj = 0; jj < 4; ++jj) {
        int nl = wc + jj*16 + m16;
        bf16x8 b = *(const bf16x8*)&Bb[(nl*8 + (cb ^ (nl & 7)))*8];
        acc[jj] = __builtin_amdgcn_mfma_f32_16x16x32_bf16(a, b, acc[jj], 0, 0, 0);
      }
    }
  }

  auto stageW = [&](const u16* W) {
#pragma unroll
    for (int it = 0; it < 8; ++it) {
      int slot = it*256 + tid, nl = slot >> 4, g = (slot & 15) ^ (nl & 15);
      gld16(W + (size_t)nl*128 + g*8, Bs + it*2048 + wv*512);
    }
  };
  auto writeH = [&](const f32x4* ac, const float* bias) {
#pragma unroll
    for (int jj = 0; jj < 4; ++jj) {
      int col = wc + jj*16 + m16;
      float bv = bias[col];
#pragma unroll
      for (int reg = 0; reg < 4; ++reg) {
        int row = wr + quad*4 + reg;
        int chunk = col >> 3;
        Hs[(row*16 + (chunk ^ (row & 15)))*8 + (col & 7)] =
            f2b(fmaxf(ac[jj][reg] + bv, 0.f));
      }
    }
  };
  auto mm128 = [&](f32x4* ac) {
#pragma unroll
    for (int ks = 0; ks < 4; ++ks) {
      int cb = ks*4 + quad;
      int ar = wr + m16;
      bf16x8 a = *(const bf16x8*)&Hs[(ar*16 + (cb ^ (ar & 15)))*8];
#pragma unroll
      for (int jj = 0; jj < 4; ++jj) {
        int nl = wc + jj*16 + m16;
        bf16x8 b = *(const bf16x8*)&Bs[(nl*16 + (cb ^ (nl & 15)))*8];
        ac[jj] = __builtin_amdgcn_mfma_f32_16x16x32_bf16(a, b, ac[jj], 0, 0, 0);
      }
    }
  };

  __syncthreads();                 // fc0 LDS reads done everywhere
  stageW(W1t);
  for (int s = tid; s < 1536; s += 256) sFw[s] = f2b(FW[s]);
  if (tid < 12) sFb[tid] = fb[tid];
  writeH(acc, b0);                 // h1 -> Hs
  __syncthreads();

  f32x4 acc2[4] = {};
  mm128(acc2);
  __syncthreads();
  stageW(W2t);
  writeH(acc2, b1);                // h2 -> Hs
  __syncthreads();

  f32x4 acc3[4] = {};
  mm128(acc3);
  __syncthreads();
  writeH(acc3, b2);                // h3 -> Hs
  __syncthreads();

  for (int s = tid; s < 512; s += 256) {
    int row = s >> 4, g = s & 15;
    bf16x8 v = *(const bf16x8*)&Hs[(row*16 + (g ^ (row & 15)))*8];
    *(bf16x8*)(h3 + (size_t)(r0 + row)*128 + g*8) = v;
  }
  for (int o = tid; o < 384; o += 256) {
    int row = o / 12, t = o - (o/12)*12;
    float a = sFb[t];
#pragma unroll
    for (int chunk = 0; chunk < 16; ++chunk) {
      const u16* hp = &Hs[(row*16 + (chunk ^ (row & 15)))*8];
#pragma unroll
      for (int jq = 0; jq < 8; ++jq)
        a = fmaf(b2f(hp[jq]), b2f(sFw[(chunk*8 + jq)*12 + t]), a);
    }
    f_acc[(size_t)(r0 + row)*12 + t] += a;
  }
}

// ---------------- k_back: BW-amortized row-loop GEMM + direct epilogue -------
// Round-8: grid (69, 20), block = 192 rows x 128 cols as 3x64-row tiles. BW
// panel staged ONCE (32KB persistent); h3 tiles double-buffered (2x16KB,
// prefetch of tile t+1 issued right after the barrier). One __syncthreads per
// tile -> short chains (the R4 regime). Staged bytes 199 -> 110 MB/launch.
// Epilogues direct from fragments: FINAL = coalesced float2 (R6-proven
// pattern); RMW = u16 read-modify-write (32B segments, L2 line-shared).
// LDS 64KB -> 2 blocks/CU resident, 5.4 queued.
template<int FINAL>
__global__ __launch_bounds__(256, 2) void k_back(
    const u16* __restrict__ h3, const u16* __restrict__ BWt,
    const float* __restrict__ bbias, u16* __restrict__ xb,
    float* __restrict__ xf)
{
  __shared__ __attribute__((aligned(16))) u16 Bsl[16384];    // 32 KB BW (persistent)
  __shared__ __attribute__((aligned(16))) u16 Asl[2][8192];  // 2x16 KB h3 dbuf
  const int tid = threadIdx.x, wv = tid >> 6, lane = tid & 63;
  const int m16 = lane & 15, quad = lane >> 4;
  const int wr2 = (wv & 1) * 32, wc2 = (wv >> 1) * 64;
  const int gr0 = blockIdx.x * 192, n0 = blockIdx.y * 128;

#pragma unroll
  for (int it = 0; it < 8; ++it) {
    int slot = it*256 + tid, nl = slot >> 4, g = (slot & 15) ^ (nl & 15);
    gld16(BWt + (size_t)(n0 + nl)*128 + g*8, Bsl + it*2048 + wv*512);
  }
  auto stageH = [&](int rt, int buf) {
#pragma unroll
    for (int it = 0; it < 4; ++it) {
      int slot = it*256 + tid, row = slot >> 4, g = (slot & 15) ^ (row & 15);
      gld16(h3 + (size_t)(gr0 + rt*64 + row)*128 + g*8, Asl[buf] + it*2048 + wv*512);
    }
  };
  float bb[4];
#pragma unroll
  for (int jj = 0; jj < 4; ++jj) bb[jj] = bbias[n0 + wc2 + jj*16 + m16];
  stageH(0, 0);

  for (int rt = 0; rt < 3; ++rt) {
    const int buf = rt & 1;
    __syncthreads();                       // drains staging for this tile
    if (rt < 2) stageH(rt + 1, buf ^ 1);   // prefetch next tile (other buffer)

    f32x4 bacc[2][4] = {};
#pragma unroll
    for (int ks = 0; ks < 4; ++ks) {
      int cb = ks*4 + quad;
      int ar0 = wr2 + m16, ar1 = wr2 + 16 + m16;
      bf16x8 a0 = *(const bf16x8*)&Asl[buf][(ar0*16 + (cb ^ (ar0 & 15)))*8];
      bf16x8 a1 = *(const bf16x8*)&Asl[buf][(ar1*16 + (cb ^ (ar1 & 15)))*8];
#pragma unroll
      for (int jj = 0; jj < 4; ++jj) {
        int nl = wc2 + jj*16 + m16;
        bf16x8 b = *(const bf16x8*)&Bsl[(nl*16 + (cb ^ (nl & 15)))*8];
        bacc[0][jj] = __builtin_amdgcn_mfma_f32_16x16x32_bf16(a0, b, bacc[0][jj], 0, 0, 0);
        bacc[1][jj] = __builtin_amdgcn_mfma_f32_16x16x32_bf16(a1, b, bacc[1][jj], 0, 0, 0);
      }
    }

    const int r0 = gr0 + rt*64;
    if constexpr (!FINAL) {
#pragma unroll
      for (int mi = 0; mi < 2; ++mi)
#pragma unroll
        for (int jj = 0; jj < 4; ++jj) {
          int col = n0 + wc2 + jj*16 + m16;
#pragma unroll
          for (int reg = 0; reg < 4; ++reg) {
            int row = r0 + wr2 + mi*16 + quad*4 + reg;
            u16* xp = xb + (size_t)row*2560 + col;
            *xp = f2b(fmaxf(b2f(*xp) - (bacc[mi][jj][reg] + bb[jj]), 0.f));
          }
        }
    } else {
#pragma unroll
      for (int mi = 0; mi < 2; ++mi)
#pragma unroll
        for (int jj = 0; jj < 4; ++jj) {
          int col = n0 + wc2 + jj*16 + m16;
#pragma unroll
          for (int pr = 0; pr < 2; ++pr) {
            int row = r0 + wr2 + mi*16 + quad*4 + pr*2;  // even; (row,row+1)=bn,c0/1
            const u16* x0 = xb + (size_t)row*2560 + col;
            const u16* x1 = x0 + 2560;
            float2 ov;
            ov.x = fmaxf(b2f(*x0) - (bacc[mi][jj][pr*2+0] + bb[jj]), 0.f);
            ov.y = fmaxf(b2f(*x1) - (bacc[mi][jj][pr*2+1] + bb[jj]), 0.f);
            *(float2*)(xf + (size_t)(row>>1)*XSTRIDE + (size_t)col*2) = ov;
          }
        }
    }
  }
}

// ---------------- finalize forecast ----------------
__global__ __launch_bounds__(256) void k_forecast(
    const float* __restrict__ f_acc, const float* __restrict__ level,
    const float* __restrict__ tgf, float* __restrict__ outf)
{
  int idx = blockIdx.x*256 + threadIdx.x;
  if (idx >= BN*24) return;
  int bn = idx / 24;
  int rem = idx - bn*24;
  int t = rem >> 1, c = rem & 1;
  float v = f_acc[bn*24 + c*12 + t];
  outf[idx] = v * level[bn*2 + c] * (1.f + tgf[bn*12 + t]);
}

extern "C" void kernel_launch(void* const* d_in, const int* in_sizes, int n_in,
                              void* d_out, int out_size, void* d_ws, size_t ws_size,
                              hipStream_t stream)
{
  const float* hist = (const float*)d_in[0];
  const float* tod  = (const float*)d_in[1];
  const float* emb  = (const float*)d_in[2];
  const float* tg1w = (const float*)d_in[3];
  const float* tg1b = (const float*)d_in[4];
  const float* tg2w = (const float*)d_in[5];
  const float* tg2b = (const float*)d_in[6];
  const float* tg3w = (const float*)d_in[7];
  const float* tg3b = (const float*)d_in[8];
  const float* fc0w = (const float*)d_in[9];
  const float* fc0b = (const float*)d_in[10];
  const float* fcw  = (const float*)d_in[11];
  const float* fcb  = (const float*)d_in[12];
  const float* forew= (const float*)d_in[13];
  const float* foreb= (const float*)d_in[14];
  const float* backw= (const float*)d_in[15];
  const float* backb= (const float*)d_in[16];

  char* w = (char*)d_ws;
  float* h_in  = (float*)w; w += 635904;     // 158976 f32
  float* level = (float*)w; w += 52992;      // 13248 f32
  float* tgf   = (float*)w; w += 317952;     // 79488 f32
  float* dp    = (float*)w; w += 171408;     // 42852 f32
  float* f_acc = (float*)w; w += 635904;     // 158976 f32
  u16* fc0wt   = (u16*)w;   w += 1966080;    // 3 x [128][2560]
  u16* fcwt    = (u16*)w;   w += 196608;     // 6 x [128][128]
  u16* backwt  = (u16*)w;   w += 1966080;    // 3 x [2560][128]
  u16* xb      = (u16*)w;   w += 67829760;   // 13248*2560 bf16
  u16* h3      = (u16*)w;   w += 3391488;    // 13248*128 bf16

  float* x    = (float*)d_out;                               // [bn][k][c] fp32
  float* outf = (float*)d_out + (size_t)BN*CONCATk*Cc;

  k_transp<<<dim3(40, 2, 3), 256, 0, stream>>>(fc0w, fc0wt, 2560, 128);
  k_transp<<<dim3(2, 2, 6), 256, 0, stream>>>(fcw, fcwt, 128, 128);
  k_transp<<<dim3(2, 40, 3), 256, 0, stream>>>(backw, backwt, 128, 2560);
  k_timegate<<<BN, 128, 0, stream>>>(hist, tod, emb, tg1w, tg1b, tg2w, tg2b,
                                     tg3w, tg3b, h_in, level, tgf, f_acc);
  k_dp<<<Nn, 256, 0, stream>>>(emb, dp);
  k_build_b<<<BN, 256, 0, stream>>>(h_in, level, dp, emb, xb);

  for (int i = 0; i < NBb; ++i) {
    const u16* W0t = fc0wt + (size_t)i*327680;
    const u16* W1t = fcwt + (size_t)(i*2+0)*16384;
    const u16* W2t = fcwt + (size_t)(i*2+1)*16384;
    const u16* BWt = backwt + (size_t)i*327680;
    k_fc<<<414, 256, 0, stream>>>(xb, W0t, fc0b + i*128, W1t, fcb + (i*2+0)*128,
                                  W2t, fcb + (i*2+1)*128, forew + (size_t)i*1536,
                                  foreb + i*12, f_acc, h3);
    if (i < NBb-1)
      k_back<0><<<dim3(69, 20), 256, 0, stream>>>(h3, BWt, backb + (size_t)i*2560,
                                                  xb, nullptr);
    else
      k_back<1><<<dim3(69, 20), 256, 0, stream>>>(h3, BWt, backb + (size_t)i*2560,
                                                  xb, x);
  }
  k_forecast<<<(BN*24 + 255)/256, 256, 0, stream>>>(f_acc, level, tgf, outf);
}

// Round 9
// 462.993 us; speedup vs baseline: 1.7300x; 1.0343x over previous
//
#include <hip/hip_runtime.h>
#include <math.h>

#define Bsz 32
#define Nn 207
#define Tt 12
#define Cc 2
#define HORr 12
#define DIDd 64
#define Hh 128
#define NBb 3
#define CONCATk 2560
#define BN (Bsz*Nn)           // 6624
#define ROWS (BN*Cc)          // 13248 = 414*32 = 69*192
#define XSTRIDE (CONCATk*Cc)  // 5120

typedef unsigned short u16;
typedef __attribute__((ext_vector_type(8))) short bf16x8;
typedef __attribute__((ext_vector_type(4))) float f32x4;

__device__ inline u16 f2b(float f) {
  unsigned u = __builtin_bit_cast(unsigned, f);
  u += 0x7fffu + ((u >> 16) & 1u);          // RNE
  return (u16)(u >> 16);
}
__device__ inline float b2f(u16 b) {
  unsigned u = ((unsigned)b) << 16;
  return __builtin_bit_cast(float, u);
}
__device__ inline void gld16(const void* g, void* l) {
  __builtin_amdgcn_global_load_lds((const __attribute__((address_space(1))) void*)g,
                                   (__attribute__((address_space(3))) void*)l, 16, 0, 0);
}

// ---------------- k_prep: 3x transp + dp + timegate in ONE launch ------------
// blockIdx.x ranges: [0,240) fc0w transp, [240,264) fcw, [264,504) backw,
// [504,711) dp, [711,4023) timegate (2 bn per block). All independent.
__global__ __launch_bounds__(256) void k_prep(
    const float* __restrict__ fc0w, u16* __restrict__ fc0wt,
    const float* __restrict__ fcw,  u16* __restrict__ fcwt,
    const float* __restrict__ backw, u16* __restrict__ backwt,
    const float* __restrict__ emb,  float* __restrict__ dp,
    const float* __restrict__ hist, const float* __restrict__ tod,
    const float* __restrict__ w1, const float* __restrict__ b1,
    const float* __restrict__ w2, const float* __restrict__ b2,
    const float* __restrict__ w3, const float* __restrict__ b3,
    float* __restrict__ h_in, float* __restrict__ level,
    float* __restrict__ tgf, float* __restrict__ f_acc)
{
  const int bid = blockIdx.x, tid = threadIdx.x;
  if (bid < 504) {
    // ---- weight transpose+convert: fp32 [K][N] -> bf16 [N][K] ----
    const float* src; u16* dst; int K, N, k0, n0;
    if (bid < 240) {            // fc0w (40,2,3), K=2560 N=128
      int z = bid/80, r = bid%80;
      src = fc0w + (size_t)z*2560*128; dst = fc0wt + (size_t)z*2560*128;
      K = 2560; N = 128; k0 = (r%40)*64; n0 = (r/40)*64;
    } else if (bid < 264) {     // fcw (2,2,6), K=128 N=128
      int b2_ = bid-240, z = b2_/4, r = b2_%4;
      src = fcw + (size_t)z*128*128; dst = fcwt + (size_t)z*128*128;
      K = 128; N = 128; k0 = (r%2)*64; n0 = (r/2)*64;
    } else {                    // backw (2,40,3), K=128 N=2560
      int b3_ = bid-264, z = b3_/80, r = b3_%80;
      src = backw + (size_t)z*128*2560; dst = backwt + (size_t)z*128*2560;
      K = 128; N = 2560; k0 = (r%2)*64; n0 = (r/2)*64;
    }
    __shared__ u16 Ts[64][72];
#pragma unroll
    for (int it = 0; it < 4; ++it) {
      int idx = it*256 + tid;
      int r = idx >> 4, q = idx & 15;
      float4 v = *(const float4*)(src + (size_t)(k0 + r)*N + n0 + q*4);
      Ts[r][q*4+0] = f2b(v.x);
      Ts[r][q*4+1] = f2b(v.y);
      Ts[r][q*4+2] = f2b(v.z);
      Ts[r][q*4+3] = f2b(v.w);
    }
    __syncthreads();
#pragma unroll
    for (int it = 0; it < 2; ++it) {
      int idx = it*256 + tid;
      int nl = idx >> 3, kq = idx & 7;
      u16 o[8];
#pragma unroll
      for (int j = 0; j < 8; ++j) o[j] = Ts[kq*8 + j][nl];
      *(bf16x8*)(dst + (size_t)(n0 + nl)*K + k0 + kq*8) = *(bf16x8*)o;
    }
  } else if (bid < 711) {
    // ---- dp[n,m] = exp(10 * <emb_n, emb_m>) ----
    int n = bid - 504;
    __shared__ float e[64];
    if (tid < 64) e[tid] = emb[n*64 + tid];
    __syncthreads();
    if (tid < Nn) {
      float a = 0.f;
#pragma unroll 8
      for (int k = 0; k < 64; ++k) a = fmaf(e[k], emb[tid*64 + k], a);
      dp[n*Nn + tid] = expf(10.f * a);
    }
  } else {
    // ---- time gates, 2 bn per block (identical control flow both halves) ----
    int pair = bid - 711;
    int half = tid >> 7, t = tid & 127;
    int bn = pair*2 + half;
    int n = bn % Nn;
    __shared__ float s_in[2][76];
    __shared__ float s_tg[2][128];
    __shared__ float s_tgb[2][12];
    __shared__ float s_h[2][24];
    __shared__ float part[2][24][4];
    if (t < 64) s_in[half][t] = emb[n*64 + t];
    else if (t < 76) s_in[half][t] = tod[bn*12 + (t - 64)];
    __syncthreads();
    float acc = b1[t];
#pragma unroll 4
    for (int k = 0; k < 76; ++k) acc = fmaf(s_in[half][k], w1[k*128 + t], acc);
    s_tg[half][t] = fmaxf(acc, 0.f);
    __syncthreads();
    if (t < 96) {
      int j = t >> 2, p = t & 3;
      int jj = (j < 12) ? j : j - 12;
      const float* w = (j < 12) ? w2 : w3;
      float a = 0.f;
#pragma unroll 8
      for (int k = p*32; k < p*32 + 32; ++k) a = fmaf(s_tg[half][k], w[k*12 + jj], a);
      part[half][j][p] = a;
    }
    __syncthreads();
    if (t < 24) {
      int jj = (t < 12) ? t : t - 12;
      float a = ((t < 12) ? b2[jj] : b3[jj])
              + part[half][t][0] + part[half][t][1]
              + part[half][t][2] + part[half][t][3];
      if (t < 12) tgf[bn*12 + jj] = a;
      else s_tgb[half][jj] = a;
    }
    __syncthreads();
    if (t < 24) {
      int tt = t >> 1;
      float v = hist[bn*24 + t] / (1.f + s_tgb[half][tt]);
      h_in[bn*24 + t] = v;
      s_h[half][t] = v;
      f_acc[bn*24 + t] = 0.f;
    }
    __syncthreads();
    if (t < 2) {
      float m = s_h[half][t];
      for (int tt = 1; tt < 12; ++tt) m = fmaxf(m, s_h[half][tt*2 + t]);
      level[bn*2 + t] = m;
    }
  }
}

// ---------------- build xb bf16, row-major [r=bn*2+c][k] ---------------------
__global__ __launch_bounds__(256) void k_build_b(
    const float* __restrict__ h_in, const float* __restrict__ level,
    const float* __restrict__ dp, const float* __restrict__ emb,
    u16* __restrict__ xb)
{
  int bn = blockIdx.x;
  int b = bn / Nn, n = bn - b*Nn;
  __shared__ float s_dp[Nn];
  __shared__ __attribute__((aligned(16))) u16 row[2][2560];
  int tid = threadIdx.x;
  for (int m = tid; m < Nn; m += 256) s_dp[m] = dp[n*Nn + m];
  float lev0 = level[bn*2], lev1 = level[bn*2+1];
  float inv0 = 1.f/(lev0+1e-8f), inv1 = 1.f/(lev1+1e-8f);
  __syncthreads();
  if (tid < Nn) {
    int m = tid;
    float dpm = s_dp[m];
    const float2* hp = (const float2*)(h_in + (size_t)(b*Nn + m)*24);
#pragma unroll
    for (int t = 0; t < 12; ++t) {
      float2 v = hp[t];
      row[0][12 + m*12 + t] = f2b(fmaxf((v.x*dpm - lev0)*inv0, 0.f));
      row[1][12 + m*12 + t] = f2b(fmaxf((v.y*dpm - lev1)*inv1, 0.f));
    }
  } else if (tid < 219) {            // history (12 t, both c)
    int t = tid - 207;
    float2 v = *(const float2*)(h_in + (size_t)bn*24 + t*2);
    row[0][t] = f2b(v.x*inv0);
    row[1][t] = f2b(v.y*inv1);
  } else if (tid < 251) {            // emb: 32 threads x 2 elems
    int e = (tid - 219)*2;
    float2 ev = *(const float2*)(emb + n*64 + e);
    u16 a = f2b(ev.x), bq = f2b(ev.y);
    row[0][2496+e] = a; row[0][2497+e] = bq;
    row[1][2496+e] = a; row[1][2497+e] = bq;
  }
  __syncthreads();
  for (int s = tid; s < 640; s += 256) {
    int c = s >= 320, ks = s - c*320;
    *(bf16x8*)(xb + (size_t)(bn*2 + c)*2560 + ks*8) = *(const bf16x8*)&row[c][ks*8];
  }
}

// ---------------- k_fc: fc0 -> h1 -> h2 -> h3 + fore; writes h3 --------------
// R4/R8 verbatim (best measured): grid 414 (32-row tiles), 256 thr / 4 waves,
// 51KB LDS, 2-buf gld16 pipeline, one barrier per K-step.
__global__ __launch_bounds__(256, 3) void k_fc(
    const u16* __restrict__ xb,
    const u16* __restrict__ W0t, const float* __restrict__ b0,
    const u16* __restrict__ W1t, const float* __restrict__ b1,
    const u16* __restrict__ W2t, const float* __restrict__ b2,
    const float* __restrict__ FW, const float* __restrict__ fb,
    float* __restrict__ f_acc, u16* __restrict__ h3)
{
  __shared__ __attribute__((aligned(16))) u16 As[2*2048];   //  8 KB A dbuf
  __shared__ __attribute__((aligned(16))) u16 Bs[2*8192];   // 32 KB B dbuf / W1,W2
  __shared__ __attribute__((aligned(16))) u16 Hs[4096];     //  8 KB h tile
  __shared__ __attribute__((aligned(16))) u16 sFw[1536];    //  3 KB FW bf16
  __shared__ float sFb[12];
  const int tid = threadIdx.x, wv = tid >> 6, lane = tid & 63;
  const int m16 = lane & 15, quad = lane >> 4;
  const int wr = (wv & 1) * 16, wc = (wv >> 1) * 64;
  const int r0 = blockIdx.x * 32;

  const int s_row = tid >> 3, s_ch = tid & 7;
  const u16* a_src = xb + (size_t)(r0 + s_row)*2560 + (s_ch ^ (s_row & 7))*8;
  u16* a_dst = As + wv*512;
  const u16* b_src[4];
#pragma unroll
  for (int it = 0; it < 4; ++it) {
    int slot = it*256 + tid, nl = slot >> 3, g = (slot & 7) ^ (nl & 7);
    b_src[it] = W0t + (size_t)nl*2560 + g*8;
  }
  u16* b_dst = Bs + wv*512;
  auto issueF = [&](int t, int buf) {
    gld16(a_src + t*64, a_dst + buf*2048);
#pragma unroll
    for (int it = 0; it < 4; ++it)
      gld16(b_src[it] + t*64, b_dst + buf*8192 + it*2048);
  };

  issueF(0, 0);
  f32x4 acc[4] = {};
  for (int j = 0; j < 40; ++j) {
    const int buf = j & 1;
    asm volatile("s_waitcnt vmcnt(0)" ::: "memory");
    __builtin_amdgcn_sched_barrier(0);
    __builtin_amdgcn_s_barrier();
    __builtin_amdgcn_sched_barrier(0);
    if (j < 39) issueF(j + 1, buf ^ 1);
    const u16* Ab = As + buf*2048;
    const u16* Bb = Bs + buf*8192;
#pragma unroll
    for (int ks = 0; ks < 2; ++ks) {
      int cb = ks*4 + quad;
      int ar = wr + m16;
      bf16x8 a = *(const bf16x8*)&Ab[(ar*8 + (cb ^ (ar & 7)))*8];
#pragma unroll
      for (int jj = 0; jj < 4; ++jj) {
        int nl = wc + jj*16 + m16;
        bf16x8 b = *(const bf16x8*)&Bb[(nl*8 + (cb ^ (nl & 7)))*8];
        acc[jj] = __builtin_amdgcn_mfma_f32_16x16x32_bf16(a, b, acc[jj], 0, 0, 0);
      }
    }
  }

  auto stageW = [&](const u16* W) {
#pragma unroll
    for (int it = 0; it < 8; ++it) {
      int slot = it*256 + tid, nl = slot >> 4, g = (slot & 15) ^ (nl & 15);
      gld16(W + (size_t)nl*128 + g*8, Bs + it*2048 + wv*512);
    }
  };
  auto writeH = [&](const f32x4* ac, const float* bias) {
#pragma unroll
    for (int jj = 0; jj < 4; ++jj) {
      int col = wc + jj*16 + m16;
      float bv = bias[col];
#pragma unroll
      for (int reg = 0; reg < 4; ++reg) {
        int row = wr + quad*4 + reg;
        int chunk = col >> 3;
        Hs[(row*16 + (chunk ^ (row & 15)))*8 + (col & 7)] =
            f2b(fmaxf(ac[jj][reg] + bv, 0.f));
      }
    }
  };
  auto mm128 = [&](f32x4* ac) {
#pragma unroll
    for (int ks = 0; ks < 4; ++ks) {
      int cb = ks*4 + quad;
      int ar = wr + m16;
      bf16x8 a = *(const bf16x8*)&Hs[(ar*16 + (cb ^ (ar & 15)))*8];
#pragma unroll
      for (int jj = 0; jj < 4; ++jj) {
        int nl = wc + jj*16 + m16;
        bf16x8 b = *(const bf16x8*)&Bs[(nl*16 + (cb ^ (nl & 15)))*8];
        ac[jj] = __builtin_amdgcn_mfma_f32_16x16x32_bf16(a, b, ac[jj], 0, 0, 0);
      }
    }
  };

  __syncthreads();                 // fc0 LDS reads done everywhere
  stageW(W1t);
  for (int s = tid; s < 1536; s += 256) sFw[s] = f2b(FW[s]);
  if (tid < 12) sFb[tid] = fb[tid];
  writeH(acc, b0);                 // h1 -> Hs
  __syncthreads();

  f32x4 acc2[4] = {};
  mm128(acc2);
  __syncthreads();
  stageW(W2t);
  writeH(acc2, b1);                // h2 -> Hs
  __syncthreads();

  f32x4 acc3[4] = {};
  mm128(acc3);
  __syncthreads();
  writeH(acc3, b2);                // h3 -> Hs
  __syncthreads();

  for (int s = tid; s < 512; s += 256) {
    int row = s >> 4, g = s & 15;
    bf16x8 v = *(const bf16x8*)&Hs[(row*16 + (g ^ (row & 15)))*8];
    *(bf16x8*)(h3 + (size_t)(r0 + row)*128 + g*8) = v;
  }
  for (int o = tid; o < 384; o += 256) {
    int row = o / 12, t = o - (o/12)*12;
    float a = sFb[t];
#pragma unroll
    for (int chunk = 0; chunk < 16; ++chunk) {
      const u16* hp = &Hs[(row*16 + (chunk ^ (row & 15)))*8];
#pragma unroll
      for (int jq = 0; jq < 8; ++jq)
        a = fmaf(b2f(hp[jq]), b2f(sFw[(chunk*8 + jq)*12 + t]), a);
    }
    f_acc[(size_t)(r0 + row)*12 + t] += a;
  }
}

// ---------------- k_back: BW-amortized row-loop GEMM + direct epilogue -------
// R8 verbatim body. FINAL=1 additionally hosts the forecast finalize at
// blockIdx.y==20 (f_acc/level/tgf complete before this launch; writes the
// disjoint outf region).
template<int FINAL>
__global__ __launch_bounds__(256, 2) void k_back(
    const u16* __restrict__ h3, const u16* __restrict__ BWt,
    const float* __restrict__ bbias, u16* __restrict__ xb,
    float* __restrict__ xf,
    const float* __restrict__ f_acc, const float* __restrict__ level,
    const float* __restrict__ tgf, float* __restrict__ outf)
{
  const int tid = threadIdx.x;
  if constexpr (FINAL) {
    if (blockIdx.y == 20) {          // fused forecast finalize
      for (int idx = blockIdx.x*256 + tid; idx < BN*24; idx += 69*256) {
        int bn = idx / 24;
        int rem = idx - bn*24;
        int t = rem >> 1, c = rem & 1;
        float v = f_acc[bn*24 + c*12 + t];
        outf[idx] = v * level[bn*2 + c] * (1.f + tgf[bn*12 + t]);
      }
      return;
    }
  }
  __shared__ __attribute__((aligned(16))) u16 Bsl[16384];    // 32 KB BW (persistent)
  __shared__ __attribute__((aligned(16))) u16 Asl[2][8192];  // 2x16 KB h3 dbuf
  const int wv = tid >> 6, lane = tid & 63;
  const int m16 = lane & 15, quad = lane >> 4;
  const int wr2 = (wv & 1) * 32, wc2 = (wv >> 1) * 64;
  const int gr0 = blockIdx.x * 192, n0 = blockIdx.y * 128;

#pragma unroll
  for (int it = 0; it < 8; ++it) {
    int slot = it*256 + tid, nl = slot >> 4, g = (slot & 15) ^ (nl & 15);
    gld16(BWt + (size_t)(n0 + nl)*128 + g*8, Bsl + it*2048 + wv*512);
  }
  auto stageH = [&](int rt, int buf) {
#pragma unroll
    for (int it = 0; it < 4; ++it) {
      int slot = it*256 + tid, row = slot >> 4, g = (slot & 15) ^ (row & 15);
      gld16(h3 + (size_t)(gr0 + rt*64 + row)*128 + g*8, Asl[buf] + it*2048 + wv*512);
    }
  };
  float bb[4];
#pragma unroll
  for (int jj = 0; jj < 4; ++jj) bb[jj] = bbias[n0 + wc2 + jj*16 + m16];
  stageH(0, 0);

  for (int rt = 0; rt < 3; ++rt) {
    const int buf = rt & 1;
    __syncthreads();                       // drains staging for this tile
    if (rt < 2) stageH(rt + 1, buf ^ 1);   // prefetch next tile (other buffer)

    f32x4 bacc[2][4] = {};
#pragma unroll
    for (int ks = 0; ks < 4; ++ks) {
      int cb = ks*4 + quad;
      int ar0 = wr2 + m16, ar1 = wr2 + 16 + m16;
      bf16x8 a0 = *(const bf16x8*)&Asl[buf][(ar0*16 + (cb ^ (ar0 & 15)))*8];
      bf16x8 a1 = *(const bf16x8*)&Asl[buf][(ar1*16 + (cb ^ (ar1 & 15)))*8];
#pragma unroll
      for (int jj = 0; jj < 4; ++jj) {
        int nl = wc2 + jj*16 + m16;
        bf16x8 b = *(const bf16x8*)&Bsl[(nl*16 + (cb ^ (nl & 15)))*8];
        bacc[0][jj] = __builtin_amdgcn_mfma_f32_16x16x32_bf16(a0, b, bacc[0][jj], 0, 0, 0);
        bacc[1][jj] = __builtin_amdgcn_mfma_f32_16x16x32_bf16(a1, b, bacc[1][jj], 0, 0, 0);
      }
    }

    const int r0 = gr0 + rt*64;
    if constexpr (!FINAL) {
#pragma unroll
      for (int mi = 0; mi < 2; ++mi)
#pragma unroll
        for (int jj = 0; jj < 4; ++jj) {
          int col = n0 + wc2 + jj*16 + m16;
#pragma unroll
          for (int reg = 0; reg < 4; ++reg) {
            int row = r0 + wr2 + mi*16 + quad*4 + reg;
            u16* xp = xb + (size_t)row*2560 + col;
            *xp = f2b(fmaxf(b2f(*xp) - (bacc[mi][jj][reg] + bb[jj]), 0.f));
          }
        }
    } else {
#pragma unroll
      for (int mi = 0; mi < 2; ++mi)
#pragma unroll
        for (int jj = 0; jj < 4; ++jj) {
          int col = n0 + wc2 + jj*16 + m16;
#pragma unroll
          for (int pr = 0; pr < 2; ++pr) {
            int row = r0 + wr2 + mi*16 + quad*4 + pr*2;  // even; (row,row+1)=bn,c0/1
            const u16* x0 = xb + (size_t)row*2560 + col;
            const u16* x1 = x0 + 2560;
            float2 ov;
            ov.x = fmaxf(b2f(*x0) - (bacc[mi][jj][pr*2+0] + bb[jj]), 0.f);
            ov.y = fmaxf(b2f(*x1) - (bacc[mi][jj][pr*2+1] + bb[jj]), 0.f);
            *(float2*)(xf + (size_t)(row>>1)*XSTRIDE + (size_t)col*2) = ov;
          }
        }
    }
  }
}

extern "C" void kernel_launch(void* const* d_in, const int* in_sizes, int n_in,
                              void* d_out, int out_size, void* d_ws, size_t ws_size,
                              hipStream_t stream)
{
  const float* hist = (const float*)d_in[0];
  const float* tod  = (const float*)d_in[1];
  const float* emb  = (const float*)d_in[2];
  const float* tg1w = (const float*)d_in[3];
  const float* tg1b = (const float*)d_in[4];
  const float* tg2w = (const float*)d_in[5];
  const float* tg2b = (const float*)d_in[6];
  const float* tg3w = (const float*)d_in[7];
  const float* tg3b = (const float*)d_in[8];
  const float* fc0w = (const float*)d_in[9];
  const float* fc0b = (const float*)d_in[10];
  const float* fcw  = (const float*)d_in[11];
  const float* fcb  = (const float*)d_in[12];
  const float* forew= (const float*)d_in[13];
  const float* foreb= (const float*)d_in[14];
  const float* backw= (const float*)d_in[15];
  const float* backb= (const float*)d_in[16];

  char* w = (char*)d_ws;
  float* h_in  = (float*)w; w += 635904;     // 158976 f32
  float* level = (float*)w; w += 52992;      // 13248 f32
  float* tgf   = (float*)w; w += 317952;     // 79488 f32
  float* dp    = (float*)w; w += 171408;     // 42852 f32
  float* f_acc = (float*)w; w += 635904;     // 158976 f32
  u16* fc0wt   = (u16*)w;   w += 1966080;    // 3 x [128][2560]
  u16* fcwt    = (u16*)w;   w += 196608;     // 6 x [128][128]
  u16* backwt  = (u16*)w;   w += 1966080;    // 3 x [2560][128]
  u16* xb      = (u16*)w;   w += 67829760;   // 13248*2560 bf16
  u16* h3      = (u16*)w;   w += 3391488;    // 13248*128 bf16

  float* x    = (float*)d_out;                               // [bn][k][c] fp32
  float* outf = (float*)d_out + (size_t)BN*CONCATk*Cc;

  k_prep<<<4023, 256, 0, stream>>>(fc0w, fc0wt, fcw, fcwt, backw, backwt,
                                   emb, dp, hist, tod, tg1w, tg1b, tg2w, tg2b,
                                   tg3w, tg3b, h_in, level, tgf, f_acc);
  k_build_b<<<BN, 256, 0, stream>>>(h_in, level, dp, emb, xb);

  for (int i = 0; i < NBb; ++i) {
    const u16* W0t = fc0wt + (size_t)i*327680;
    const u16* W1t = fcwt + (size_t)(i*2+0)*16384;
    const u16* W2t = fcwt + (size_t)(i*2+1)*16384;
    const u16* BWt = backwt + (size_t)i*327680;
    k_fc<<<414, 256, 0, stream>>>(xb, W0t, fc0b + i*128, W1t, fcb + (i*2+0)*128,
                                  W2t, fcb + (i*2+1)*128, forew + (size_t)i*1536,
                                  foreb + i*12, f_acc, h3);
    if (i < NBb-1)
      k_back<0><<<dim3(69, 20), 256, 0, stream>>>(h3, BWt, backb + (size_t)i*2560,
                                                  xb, nullptr,
                                                  nullptr, nullptr, nullptr, nullptr);
    else
      k_back<1><<<dim3(69, 21), 256, 0, stream>>>(h3, BWt, backb + (size_t)i*2560,
                                                  xb, x,
                                                  f_acc, level, tgf, outf);
  }
}